// Round 9
// baseline (108027.881 us; speedup 1.0000x reference)
//
#include <hip/hip_runtime.h>

#define NSAMP 16384
#define NSTEP 32

typedef __attribute__((ext_vector_type(8))) short bf16x8;
typedef __attribute__((ext_vector_type(4))) short short4v;
typedef __attribute__((ext_vector_type(4))) float f32x4;
typedef __attribute__((ext_vector_type(2))) unsigned int uint2v;
typedef __attribute__((ext_vector_type(4))) unsigned int uint4v;

__device__ __forceinline__ unsigned short f2bf(float f) {
    unsigned int u = __float_as_uint(f);
    u += 0x7FFFu + ((u >> 16) & 1u);
    return (unsigned short)(u >> 16);
}
__device__ __forceinline__ float bf2fs(short h) {
    return __uint_as_float(((unsigned int)(unsigned short)h) << 16);
}
__device__ __forceinline__ unsigned int cvtpk(float a, float b) {
    unsigned int r;
    asm("v_cvt_pk_bf16_f32 %0, %1, %2" : "=v"(r) : "v"(a), "v"(b));
    return r;
}
__device__ __forceinline__ float ftanh(float x) {
    float e = __expf(2.0f * x);
    return 1.0f - __fdividef(2.0f, e + 1.0f);
}

// ---------------- prep: pack weights to bf16 in d_ws (unchanged) ----------------
__global__ void prep_kernel(const float* __restrict__ W1, const float* __restrict__ W2,
                            const float* __restrict__ W3, const float* __restrict__ W4,
                            unsigned short* __restrict__ ws) {
    int j = blockIdx.x * blockDim.x + threadIdx.x;   // 0..65535
    if (j < 65536) {
        int e = j & 7, l = (j >> 3) & 63, s = (j >> 9) & 1, ks = (j >> 10) & 7, w = j >> 13;
        int m = (w << 5) + (s << 4) + (l & 15);
        int k = (ks << 5) + ((l >> 4) << 3) + e;
        ws[j]         = f2bf(W2[m * 256 + k]);
        ws[65536 + j] = f2bf(W3[m * 256 + k]);
    }
    if (j < 16384) {
        int i = j >> 8, k = j & 255;
        ws[131072 + j] = f2bf(W1[k * 64 + i]);   // W1T[i][k]  (L2-resident reads)
        ws[147456 + j] = f2bf(W4[j]);            // W4 [i][k]  (L2-resident reads)
        int e = j & 7, l = (j >> 3) & 63, ms = (j >> 9) & 1, ks = (j >> 10) & 1, w = j >> 11;
        int m = (w << 5) + (ms << 4) + (l & 15);
        int i2 = (ks << 5) + ((l >> 4) << 3) + e;
        ws[163840 + j] = f2bf(W1[m * 64 + i2]);  // W1 A-frags (K=64)
    }
}

// ---------------- main kernel: two phase-staggered sample pairs ----------------
// Block = 4 samples (pair0 = samples 0,1; pair1 = 2,3), 8 waves.
// Pair phases P1..P6 as in R5; pair1 runs offset by 3 phases so its VALU
// phases hide under pair0's GEMM phases (and vice versa). Shared barriers.
// W2/W3 MFMA A-frags register-resident; W1T/W4/w1-frags read from global (L2).

#define MFMA(A, B, C) __builtin_amdgcn_mfma_f32_16x16x32_bf16(A, B, C, 0, 0, 0)

#define ZERO5(ACC)                                                           \
    _Pragma("unroll") for (int ms = 0; ms < 2; ++ms)                         \
    _Pragma("unroll") for (int ns = 0; ns < 5; ++ns)                         \
        ACC[ms][ns] = (f32x4){0.f, 0.f, 0.f, 0.f};

#define ZERO4(ACC)                                                           \
    _Pragma("unroll") for (int ms = 0; ms < 2; ++ms)                         \
    _Pragma("unroll") for (int ns = 0; ns < 4; ++ns)                         \
        ACC[ms][ns] = (f32x4){0.f, 0.f, 0.f, 0.f};

#define GEMM_A(P, WF, HBASE, ACC)                                            \
    __builtin_amdgcn_s_setprio(1);                                           \
    _Pragma("unroll") for (int ks = 0; ks < 8; ++ks) {                       \
        const int kr = (ks << 5) + kband;                                    \
        bf16x8 bfr[5];                                                       \
        _Pragma("unroll") for (int ns = 0; ns < 4; ++ns)                     \
            bfr[ns] = *(const bf16x8*)&XTb[P][((ns << 4) + lm) * 264 + kr];  \
        bfr[4] = *(const bf16x8*)&XTb[P][((HBASE) + (lm & 1)) * 264 + kr];   \
        _Pragma("unroll") for (int ms = 0; ms < 2; ++ms)                     \
        _Pragma("unroll") for (int ns = 0; ns < 5; ++ns)                     \
            ACC[ms][ns] = MFMA(WF[ks][ms], bfr[ns], ACC[ms][ns]);            \
    }                                                                        \
    __builtin_amdgcn_s_setprio(0);

#define GEMM_B(P, WF, ACC)                                                   \
    __builtin_amdgcn_s_setprio(1);                                           \
    _Pragma("unroll") for (int ks = 0; ks < 8; ++ks) {                       \
        const int kr = (ks << 5) + kband;                                    \
        bf16x8 bfr[4];                                                       \
        _Pragma("unroll") for (int ns = 0; ns < 4; ++ns)                     \
            bfr[ns] = *(const bf16x8*)&XTb[P][(((ns + 4) << 4) + lm) * 264 + kr]; \
        _Pragma("unroll") for (int ms = 0; ms < 2; ++ms)                     \
        _Pragma("unroll") for (int ns = 0; ns < 4; ++ns)                     \
            ACC[ms][ns] = MFMA(WF[ks][ms], bfr[ns], ACC[ms][ns]);            \
    }                                                                        \
    __builtin_amdgcn_s_setprio(0);

#define TANH4(AZ, BL, RB, HH, DD)                                            \
    _Pragma("unroll") for (int rg = 0; rg < 4; ++rg) {                       \
        float h_ = ftanh((AZ)[rg] + BL[(RB) + rg]);                          \
        HH[rg] = h_; DD[rg] = 1.f - h_ * h_;                                 \
    }

// tangent build: wave writes XT[P] rows S*64+l, k-cols [kcol0,kcol0+32)
#define BUILD(P, S)                                                          \
    { _Pragma("unroll") for (int c = 0; c < 4; ++c) {                        \
        const int kk = kcol0 + (c << 3);                                     \
        const bf16x8 wv = *(const bf16x8*)&wsW1T[l * 256 + kk];              \
        const bf16x8 dq = *(const bf16x8*)&dv1[P][(S) * 256 + kk];           \
        uint4v o;                                                            \
        o[0] = cvtpk(bf2fs(wv[0]) * bf2fs(dq[0]), bf2fs(wv[1]) * bf2fs(dq[1])); \
        o[1] = cvtpk(bf2fs(wv[2]) * bf2fs(dq[2]), bf2fs(wv[3]) * bf2fs(dq[3])); \
        o[2] = cvtpk(bf2fs(wv[4]) * bf2fs(dq[4]), bf2fs(wv[5]) * bf2fs(dq[5])); \
        o[3] = cvtpk(bf2fs(wv[6]) * bf2fs(dq[6]), bf2fs(wv[7]) * bf2fs(dq[7])); \
        *(uint4v*)&XTb[P][((S) * 64 + l) * 264 + kk] = o;                    \
    } }

// P1: deferred logp(eval LIT-1) + z-MFMA -> h1/d1 + BUILD s0
#define PH1(P, LIT)                                                          \
    {                                                                        \
        if ((LIT) > 0 && tid < 2) {                                          \
            float div_ = 0.f;                                                \
            _Pragma("unroll") for (int q = 0; q < 8; ++q) div_ += wredp[P][tid * 8 + q]; \
            const int ep_ = ((LIT) - 1) & 3;                                 \
            const float wgt_ = (ep_ == 0 || ep_ == 3) ? 1.f : 2.f;           \
            float kl_ = (ep_ == 0) ? -div_ : misc[P][tid] - wgt_ * div_;     \
            misc[P][tid] = kl_;                                              \
            if (ep_ == 3) misc[P][2 + tid] += (DT / 6.0f) * kl_;             \
        }                                                                    \
        f32x4 az0 = (f32x4){0.f,0.f,0.f,0.f}, az1 = (f32x4){0.f,0.f,0.f,0.f};\
        _Pragma("unroll") for (int ks = 0; ks < 2; ++ks) {                   \
            const bf16x8 zf = *(const bf16x8*)&ZBTb[P][lm * 72 + (ks << 5) + kband]; \
            az0 = MFMA(w1g[(((w << 1) + ks) * 2 + 0) * 64 + l], zf, az0);    \
            az1 = MFMA(w1g[(((w << 1) + ks) * 2 + 1) * 64 + l], zf, az1);    \
        }                                                                    \
        float hh[4], dd[4];                                                  \
        TANH4(az0, b1l, r0, hh, dd)                                          \
        if (lm < 2) {                                                        \
            uint2v dp; dp[0] = cvtpk(dd[0], dd[1]); dp[1] = cvtpk(dd[2], dd[3]); \
            *(uint2v*)&dv1[P][lm * 256 + r0] = dp;                           \
            uint2v hp; hp[0] = cvtpk(hh[0], hh[1]); hp[1] = cvtpk(hh[2], hh[3]); \
            *(uint2v*)&XTb[P][(128 + lm) * 264 + r0] = hp;                   \
        }                                                                    \
        TANH4(az1, b1l, r0 + 16, hh, dd)                                     \
        if (lm < 2) {                                                        \
            uint2v dp; dp[0] = cvtpk(dd[0], dd[1]); dp[1] = cvtpk(dd[2], dd[3]); \
            *(uint2v*)&dv1[P][lm * 256 + r0 + 16] = dp;                      \
            uint2v hp; hp[0] = cvtpk(hh[0], hh[1]); hp[1] = cvtpk(hh[2], hh[3]); \
            *(uint2v*)&XTb[P][(128 + lm) * 264 + r0 + 16] = hp;              \
        }                                                                    \
        BUILD(P, 0)                                                          \
    }

// P2: BUILD s1 + GEMM1 pass A
#define PH2(P, ACC)                                                          \
    {                                                                        \
        BUILD(P, 1)                                                          \
        ZERO5(ACC)                                                           \
        GEMM_A(P, w2f, 128, ACC)                                             \
    }

// P3: epi2A (h2/d2; A2-s0 scale-write via shfl d2) + GEMM1 pass B
#define PH3(P, ACC)                                                          \
    {                                                                        \
        float d2s[2][4];                                                     \
        _Pragma("unroll") for (int ms = 0; ms < 2; ++ms) {                   \
            const int rb = r0 + (ms << 4);                                   \
            float hh[4];                                                     \
            TANH4(ACC[ms][4], b2l, rb, hh, d2s[ms])                          \
            if (lm < 2) {                                                    \
                uint2v dp; dp[0] = cvtpk(d2s[ms][0], d2s[ms][1]);            \
                dp[1] = cvtpk(d2s[ms][2], d2s[ms][3]);                       \
                *(uint2v*)&d2v[P][lm * 256 + rb] = dp;                       \
                uint2v hp; hp[0] = cvtpk(hh[0], hh[1]); hp[1] = cvtpk(hh[2], hh[3]); \
                *(uint2v*)&XTb[P][(130 + lm) * 264 + rb] = hp;               \
            }                                                                \
        }                                                                    \
        _Pragma("unroll") for (int ms = 0; ms < 2; ++ms) {                   \
            const int rb = r0 + (ms << 4);                                   \
            float ds[4];                                                     \
            _Pragma("unroll") for (int rg = 0; rg < 4; ++rg)                 \
                ds[rg] = __shfl(d2s[ms][rg], l & 48, 64);                    \
            _Pragma("unroll") for (int ns = 0; ns < 4; ++ns) {               \
                uint2v o;                                                    \
                o[0] = cvtpk(ACC[ms][ns][0] * ds[0], ACC[ms][ns][1] * ds[1]);\
                o[1] = cvtpk(ACC[ms][ns][2] * ds[2], ACC[ms][ns][3] * ds[3]);\
                *(uint2v*)&XTb[P][((ns << 4) + lm) * 264 + rb] = o;          \
            }                                                                \
        }                                                                    \
        ZERO4(ACC)                                                           \
        GEMM_B(P, w2f, ACC)                                                  \
    }

// P4: A2-s1 scale-write (d2 from LDS) + GEMM2 pass A
#define PH4(P, ACC)                                                          \
    {                                                                        \
        _Pragma("unroll") for (int ms = 0; ms < 2; ++ms) {                   \
            const int rb = r0 + (ms << 4);                                   \
            const short4v dq = *(const short4v*)&d2v[P][256 + rb];           \
            const float d0_ = bf2fs(dq[0]), d1_ = bf2fs(dq[1]);              \
            const float d2_ = bf2fs(dq[2]), d3_ = bf2fs(dq[3]);              \
            _Pragma("unroll") for (int ns = 0; ns < 4; ++ns) {               \
                uint2v o;                                                    \
                o[0] = cvtpk(ACC[ms][ns][0] * d0_, ACC[ms][ns][1] * d1_);    \
                o[1] = cvtpk(ACC[ms][ns][2] * d2_, ACC[ms][ns][3] * d3_);    \
                *(uint2v*)&XTb[P][(((ns + 4) << 4) + lm) * 264 + rb] = o;    \
            }                                                                \
        }                                                                    \
        ZERO5(ACC)                                                           \
        GEMM_A(P, w3f, 130, ACC)                                             \
    }

// P5: epi3A (h3 write, div-s0) + GEMM2 pass B + div-s1 (shfl d3) + reduce
#define PH5(P, ACC)                                                          \
    {                                                                        \
        float d3s[2][4];                                                     \
        float p0 = 0.f, p1 = 0.f;                                            \
        _Pragma("unroll") for (int ms = 0; ms < 2; ++ms) {                   \
            const int rb = r0 + (ms << 4);                                   \
            float hh[4];                                                     \
            TANH4(ACC[ms][4], b3l, rb, hh, d3s[ms])                          \
            if (lm < 2) {                                                    \
                uint2v hp; hp[0] = cvtpk(hh[0], hh[1]); hp[1] = cvtpk(hh[2], hh[3]); \
                *(uint2v*)&hvv[P][lm * 256 + rb] = hp;                       \
            }                                                                \
        }                                                                    \
        _Pragma("unroll") for (int ms = 0; ms < 2; ++ms) {                   \
            const int rb = r0 + (ms << 4);                                   \
            float ds[4];                                                     \
            _Pragma("unroll") for (int rg = 0; rg < 4; ++rg)                 \
                ds[rg] = __shfl(d3s[ms][rg], l & 48, 64);                    \
            _Pragma("unroll") for (int ns = 0; ns < 4; ++ns) {               \
                const short4v wv = *(const short4v*)&wsW4[((ns << 4) + lm) * 256 + rb]; \
                p0 += ACC[ms][ns][0] * ds[0] * bf2fs(wv[0]);                 \
                p0 += ACC[ms][ns][1] * ds[1] * bf2fs(wv[1]);                 \
                p0 += ACC[ms][ns][2] * ds[2] * bf2fs(wv[2]);                 \
                p0 += ACC[ms][ns][3] * ds[3] * bf2fs(wv[3]);                 \
            }                                                                \
        }                                                                    \
        ZERO4(ACC)                                                           \
        GEMM_B(P, w3f, ACC)                                                  \
        _Pragma("unroll") for (int ms = 0; ms < 2; ++ms) {                   \
            const int rb = r0 + (ms << 4);                                   \
            float ds[4];                                                     \
            _Pragma("unroll") for (int rg = 0; rg < 4; ++rg)                 \
                ds[rg] = __shfl(d3s[ms][rg], (l & 48) + 1, 64);              \
            _Pragma("unroll") for (int ns = 0; ns < 4; ++ns) {               \
                const short4v wv = *(const short4v*)&wsW4[((ns << 4) + lm) * 256 + rb]; \
                p1 += ACC[ms][ns][0] * ds[0] * bf2fs(wv[0]);                 \
                p1 += ACC[ms][ns][1] * ds[1] * bf2fs(wv[1]);                 \
                p1 += ACC[ms][ns][2] * ds[2] * bf2fs(wv[2]);                 \
                p1 += ACC[ms][ns][3] * ds[3] * bf2fs(wv[3]);                 \
            }                                                                \
        }                                                                    \
        _Pragma("unroll") for (int o_ = 32; o_; o_ >>= 1) {                  \
            p0 += __shfl_xor(p0, o_, 64);                                    \
            p1 += __shfl_xor(p1, o_, 64);                                    \
        }                                                                    \
        if (l == 0) { wredp[P][w] = p0; wredp[P][8 + w] = p1; }              \
    }

// P6: dz matvec + RK update (per-lane state) + ZBT write
#define PH6(P, E)                                                            \
    {                                                                        \
        const int ch = l >> 4;                                               \
        float a_ = 0.f;                                                      \
        _Pragma("unroll") for (int c = 0; c < 8; ++c) {                      \
            const bf16x8 wv = *(const bf16x8*)&wsW4[iown * 256 + (ch << 6) + (c << 3)]; \
            const bf16x8 hb = *(const bf16x8*)&hvv[P][sown * 256 + (ch << 6) + (c << 3)]; \
            a_ += bf2fs(wv[0]) * bf2fs(hb[0]) + bf2fs(wv[1]) * bf2fs(hb[1]); \
            a_ += bf2fs(wv[2]) * bf2fs(hb[2]) + bf2fs(wv[3]) * bf2fs(hb[3]); \
            a_ += bf2fs(wv[4]) * bf2fs(hb[4]) + bf2fs(wv[5]) * bf2fs(hb[5]); \
            a_ += bf2fs(wv[6]) * bf2fs(hb[6]) + bf2fs(wv[7]) * bf2fs(hb[7]); \
        }                                                                    \
        a_ += __shfl_xor(a_, 16, 64);                                        \
        a_ += __shfl_xor(a_, 32, 64);                                        \
        const float dz_ = a_ + b4r;                                          \
        const float wgt_ = ((E) == 0 || (E) == 3) ? 1.f : 2.f;               \
        const float kv_ = ((E) == 0) ? dz_ : krg[P] + wgt_ * dz_;            \
        krg[P] = kv_;                                                        \
        float znew_;                                                         \
        if ((E) < 3) {                                                       \
            znew_ = zrg[P] + (((E) == 2) ? 1.0f : 0.5f) * DT * dz_;          \
        } else {                                                             \
            znew_ = zrg[P] + (DT / 6.0f) * kv_;                              \
            zrg[P] = znew_;                                                  \
        }                                                                    \
        if (l < 16) ZBTb[P][sown * 72 + iown] = f2bf(znew_);                 \
    }

__launch_bounds__(512, 2)
__global__ void cnf_kernel(const float* __restrict__ zin,
                           const float* __restrict__ b1g, const float* __restrict__ b2g,
                           const float* __restrict__ b3g, const float* __restrict__ b4g,
                           const unsigned short* __restrict__ ws,
                           float* __restrict__ out)
{
    __shared__ __align__(16) unsigned short XTb[2][132 * 264];   // 139.4 KB
    __shared__ __align__(16) unsigned short ZBTb[2][16 * 72];    // 4.6 KB
    __shared__ __align__(16) unsigned short dv1[2][512];         // bf16 d1
    __shared__ __align__(16) unsigned short d2v[2][512];         // bf16 d2
    __shared__ __align__(16) unsigned short hvv[2][512];         // bf16 h3
    __shared__ __align__(16) float b1l[256], b2l[256], b3l[256];
    __shared__ float wredp[2][16];
    __shared__ float misc[2][4];

    const int tid = threadIdx.x;
    const int w = tid >> 6;
    const int l = tid & 63;
    const int lm = l & 15;
    const int bid = blockIdx.x;
    const int r0 = (w << 5) + ((l >> 4) << 2);
    const int kband = (l >> 4) << 3;
    const int kcol0 = w << 5;
    const float DT = -1.0f / 32.0f;

    const unsigned short* wsW1T = ws + 131072;
    const unsigned short* wsW4  = ws + 147456;
    const bf16x8* w1g = (const bf16x8*)(ws + 163840);

    // per-lane RK state (wave w owns sample sown of each pair, dims iown)
    const int sown = w >> 2;
    const int iown = ((w & 3) << 4) + lm;
    const float b4r = b4g[iown];
    float zrg[2], krg[2];
    zrg[0] = zin[(bid * 4 + sown) * 64 + iown];
    zrg[1] = zin[(bid * 4 + 2 + sown) * 64 + iown];
    krg[0] = 0.f; krg[1] = 0.f;

    // register-resident W2/W3 fragments
    bf16x8 w2f[8][2], w3f[8][2];
    {
        const bf16x8* w2g = (const bf16x8*)ws;
        const bf16x8* w3g = w2g + 8192;
#pragma unroll
        for (int ks = 0; ks < 8; ++ks)
#pragma unroll
            for (int s = 0; s < 2; ++s) {
                int idx = (((w << 3) + ks) * 2 + s) * 64 + l;
                w2f[ks][s] = w2g[idx];
                w3f[ks][s] = w3g[idx];
            }
    }
    // LDS init
#pragma unroll
    for (int P = 0; P < 2; ++P) {
        for (int c = 144 + tid; c < 1152; c += 512) ZBTb[P][c] = 0;
        if (tid < 128) {
            const int s = tid >> 6, i = tid & 63;
            ZBTb[P][s * 72 + i] = f2bf(zin[(bid * 4 + P * 2 + s) * 64 + i]);
        }
    }
    if (tid < 256) { b1l[tid] = b1g[tid]; b2l[tid] = b2g[tid]; b3l[tid] = b3g[tid]; }
    if (tid < 2) { misc[0][tid] = 0.f; misc[0][2 + tid] = 0.f;
                   misc[1][tid] = 0.f; misc[1][2 + tid] = 0.f; }
    __syncthreads();

    f32x4 accA[2][5], accB[2][5];

    // ---- prologue: pair 0 runs P1..P3 alone ----
    PH1(0, 0)            __syncthreads();
    PH2(0, accA)         __syncthreads();
    PH3(0, accA)         __syncthreads();

    for (int it = 0; it < NSTEP * 4; ++it) {
        const int e = it & 3;
        // C4: P4(A,it) + P1(B,it)
        PH4(0, accA)  PH1(1, it)         __syncthreads();
        // C5: P5(A,it) + P2(B,it)
        PH5(0, accA)  PH2(1, accB)       __syncthreads();
        // C6: P6(A,it) + P3(B,it)
        PH6(0, e)     PH3(1, accB)       __syncthreads();
        if (it < NSTEP * 4 - 1) {
            // C1: P1(A,it+1) + P4(B,it)
            PH1(0, it + 1)  PH4(1, accB) __syncthreads();
            // C2: P2(A,it+1) + P5(B,it)
            PH2(0, accA)    PH5(1, accB) __syncthreads();
            // C3: P3(A,it+1) + P6(B,it)
            PH3(0, accA)    PH6(1, e)    __syncthreads();
        }
    }
    // ---- epilogue: pair 1 finishes eval 127 ----
    PH4(1, accB)  __syncthreads();
    PH5(1, accB)  __syncthreads();
    PH6(1, 3)     __syncthreads();

    // final deferred logp (eval 127 wredp for both pairs)
    if (tid < 2) {
        float dv0 = 0.f, dvb = 0.f;
#pragma unroll
        for (int q = 0; q < 8; ++q) { dv0 += wredp[0][tid * 8 + q]; dvb += wredp[1][tid * 8 + q]; }
        float kl0 = misc[0][tid] - dv0;
        float kl1 = misc[1][tid] - dvb;
        out[NSAMP * 64 + bid * 4 + tid]     = misc[0][2 + tid] + (DT / 6.0f) * kl0;
        out[NSAMP * 64 + bid * 4 + 2 + tid] = misc[1][2 + tid] + (DT / 6.0f) * kl1;
    }
    if (l < 16) {
        out[(bid * 4 + sown) * 64 + iown]     = zrg[0];
        out[(bid * 4 + 2 + sown) * 64 + iown] = zrg[1];
    }
}

extern "C" void kernel_launch(void* const* d_in, const int* in_sizes, int n_in,
                              void* d_out, int out_size, void* d_ws, size_t ws_size,
                              hipStream_t stream) {
    const float* z  = (const float*)d_in[0];
    const float* W1 = (const float*)d_in[1];
    const float* b1 = (const float*)d_in[2];
    const float* W2 = (const float*)d_in[3];
    const float* b2 = (const float*)d_in[4];
    const float* W3 = (const float*)d_in[5];
    const float* b3 = (const float*)d_in[6];
    const float* W4 = (const float*)d_in[7];
    const float* b4 = (const float*)d_in[8];
    unsigned short* ws = (unsigned short*)d_ws;
    float* out = (float*)d_out;

    hipLaunchKernelGGL(prep_kernel, dim3(256), dim3(256), 0, stream, W1, W2, W3, W4, ws);
    hipLaunchKernelGGL(cnf_kernel, dim3(NSAMP / 4), dim3(512), 0, stream, z, b1, b2, b3, b4, ws, out);
}